// Round 1
// 603.303 us; speedup vs baseline: 1.1250x; 1.1250x over previous
//
#include <hip/hip_runtime.h>

#define BB 64
#define SS 2048
#define DD 1024
#define SCHUNK 128
#define NC (SS / SCHUNK)   // 16 s-chunks

typedef float f32x4 __attribute__((ext_vector_type(4)));

// Pass 1: per (b, s-chunk) masked partial sum over D.
// Key change vs previous version: rows with mask==0 contribute exactly 0.0f
// to the masked sum, and the full-sum fallback is only consumed when cnt==0
// (never on this data, handled in pass 2). So we SKIP ~50% of the 512 MiB
// hidden read entirely. Row indices with m==1 are compacted into LDS via
// wave ballots; the hot loop streams only selected 4-KiB rows, 8 loads in
// flight per wave, ascending s-order => bitwise-identical sums to before.
__global__ __launch_bounds__(256) void ep_partial(
    const float* __restrict__ hidden, const int* __restrict__ mask,
    float* __restrict__ wsm, float* __restrict__ wscnt)
{
    const int b  = blockIdx.x;
    const int c  = blockIdx.y;
    const int s0 = c * SCHUNK;
    const int t  = threadIdx.x;

    __shared__ unsigned char sidx[SCHUNK];
    __shared__ int s_wcnt[2];
    __shared__ int s_n;

    // --- ballot compaction: waves 0,1 classify the 128 mask entries ---
    const int lane = t & 63;
    const int w    = t >> 6;
    int m = 0;
    if (t < SCHUNK) m = (mask[b * SS + s0 + t] != 0) ? 1 : 0;
    const unsigned long long bal = __ballot(m);          // waves 2,3: bal==0
    const int pre = __popcll(bal & ((1ull << lane) - 1ull));
    if (t < SCHUNK && lane == 0) s_wcnt[w] = __popcll(bal);
    __syncthreads();
    if (m) sidx[(w ? s_wcnt[0] : 0) + pre] = (unsigned char)t;
    if (t == 0) s_n = s_wcnt[0] + s_wcnt[1];
    __syncthreads();
    const int n1 = s_n;

    // --- stream only the selected rows; thread t owns float4 column t ---
    const f32x4* hp = reinterpret_cast<const f32x4*>(
        hidden + ((size_t)b * SS + s0) * DD) + t;

    f32x4 am = {0.f, 0.f, 0.f, 0.f};

    int i = 0;
    for (; i + 8 <= n1; i += 8) {
        const int i0 = sidx[i + 0], i1 = sidx[i + 1];
        const int i2 = sidx[i + 2], i3 = sidx[i + 3];
        const int i4 = sidx[i + 4], i5 = sidx[i + 5];
        const int i6 = sidx[i + 6], i7 = sidx[i + 7];
        f32x4 v0 = __builtin_nontemporal_load(hp + (size_t)i0 * (DD / 4));
        f32x4 v1 = __builtin_nontemporal_load(hp + (size_t)i1 * (DD / 4));
        f32x4 v2 = __builtin_nontemporal_load(hp + (size_t)i2 * (DD / 4));
        f32x4 v3 = __builtin_nontemporal_load(hp + (size_t)i3 * (DD / 4));
        f32x4 v4 = __builtin_nontemporal_load(hp + (size_t)i4 * (DD / 4));
        f32x4 v5 = __builtin_nontemporal_load(hp + (size_t)i5 * (DD / 4));
        f32x4 v6 = __builtin_nontemporal_load(hp + (size_t)i6 * (DD / 4));
        f32x4 v7 = __builtin_nontemporal_load(hp + (size_t)i7 * (DD / 4));
        // single accumulator, ascending order: bitwise-identical to the
        // previous kernel's mask-FMA accumulation (adding exact zeros).
        am += v0; am += v1; am += v2; am += v3;
        am += v4; am += v5; am += v6; am += v7;
    }
    for (; i < n1; ++i)
        am += __builtin_nontemporal_load(hp + (size_t)sidx[i] * (DD / 4));

    reinterpret_cast<f32x4*>(wsm)[(size_t)(b * NC + c) * (DD / 4) + t] = am;
    if (t == 0) wscnt[b * NC + c] = (float)n1;
}

// Pass 2: 256 blocks (b x quarter-of-D), one wave each. Sums the 16 chunk
// partials + chunk counts, divides. cnt==0 fallback (never taken on this
// data) recomputes the full mean directly from hidden.
__global__ __launch_bounds__(64) void ep_finalize(
    const float* __restrict__ wsm, const float* __restrict__ wscnt,
    const float* __restrict__ hidden, float* __restrict__ out)
{
    const int b    = blockIdx.x;
    const int q    = blockIdx.y;            // D quarter
    const int lane = threadIdx.x;           // 0..63
    const int d4   = q * 64 + lane;         // float4 column in [0,256)

    float cnt = 0.f;
    #pragma unroll
    for (int c = 0; c < NC; ++c) cnt += wscnt[b * NC + c];   // uniform -> s_loads

    const f32x4* pm = reinterpret_cast<const f32x4*>(wsm)
                      + (size_t)b * NC * (DD / 4) + d4;
    f32x4 am = {0.f, 0.f, 0.f, 0.f};
    #pragma unroll
    for (int c = 0; c < NC; ++c) am += pm[(size_t)c * (DD / 4)];

    f32x4 r;
    if (cnt > 0.f) {
        r.x = am.x / cnt; r.y = am.y / cnt; r.z = am.z / cnt; r.w = am.w / cnt;
    } else {
        // all-zero mask row: full mean (cold path, kept for correctness)
        const f32x4* hp = reinterpret_cast<const f32x4*>(hidden)
                          + (size_t)b * SS * (DD / 4) + d4;
        f32x4 af = {0.f, 0.f, 0.f, 0.f};
        for (int s = 0; s < SS; ++s) af += hp[(size_t)s * (DD / 4)];
        const float invS = 1.0f / (float)SS;
        r.x = af.x * invS; r.y = af.y * invS; r.z = af.z * invS; r.w = af.w * invS;
    }
    reinterpret_cast<f32x4*>(out)[(size_t)b * (DD / 4) + d4] = r;
}

extern "C" void kernel_launch(void* const* d_in, const int* in_sizes, int n_in,
                              void* d_out, int out_size, void* d_ws, size_t ws_size,
                              hipStream_t stream) {
    const float* hidden = (const float*)d_in[0];
    const int*   mask   = (const int*)d_in[1];
    float*       out    = (float*)d_out;

    // workspace: [B*NC*D] masked partials (4 MiB) | [B*NC] chunk counts
    float* wsm   = (float*)d_ws;
    float* wscnt = wsm + (size_t)BB * NC * DD;

    ep_partial<<<dim3(BB, NC), 256, 0, stream>>>(hidden, mask, wsm, wscnt);
    ep_finalize<<<dim3(BB, 4), 64, 0, stream>>>(wsm, wscnt, hidden, out);
}